// Round 1
// baseline (48.181 us; speedup 1.0000x reference)
//
#include <hip/hip_runtime.h>
#include <hip/hip_bf16.h>

#define A_ 8
#define B_ 256
#define I_ 256
#define J_ 256
#define K_ 256

typedef __attribute__((ext_vector_type(8))) short short8_t;
typedef __attribute__((ext_vector_type(4))) float f32x4_t;

static __device__ __forceinline__ uint pack2bf(float a, float b) {
  float2 f2; f2.x = a; f2.y = b;
  __hip_bfloat162 h2 = __float22bfloat162_rn(f2);
  uint r;
  __builtin_memcpy(&r, &h2, 4);
  return r;
}

static __device__ __forceinline__ ushort f2bf(float f) {
  __hip_bfloat16 h = __float2bfloat16(f);
  ushort us;
  __builtin_memcpy(&us, &h, 2);
  return us;
}

static __device__ __forceinline__ float bf2f(ushort h) {
  uint u = ((uint)h) << 16;
  float f;
  __builtin_memcpy(&f, &u, 4);
  return f;
}

// ---------------------------------------------------------------------------
// Pass 1: u[b][i][k] = sum_j c[b][j] * w[i][j][k]   (u stored as bf16)
// Batched GEMM over i: per block, one i, a 128(b) x 128(k) tile, K-loop over j.
// ---------------------------------------------------------------------------
#define BM 128
#define BN 128
#define BK 32
#define LDA 40   // As row length in ushort (pad 32 -> 40; 80B row, 16B-aligned)
#define LDB 130  // Bs row length in ushort (pad 128 -> 130; conflict-free u16 frag reads)

__global__ __launch_bounds__(256, 2) void pass1_kernel(
    const float* __restrict__ cmat, const float* __restrict__ w,
    ushort* __restrict__ u) {
  const int i  = blockIdx.x;
  const int b0 = blockIdx.y * BM;
  const int k0 = blockIdx.z * BN;
  const int tid  = threadIdx.x;
  const int lane = tid & 63;
  const int wave = tid >> 6;
  const int wr = wave >> 1;  // wave row in b
  const int wc = wave & 1;   // wave col in k

  __shared__ ushort As[BM][LDA];  // [b][j] bf16
  __shared__ ushort Bs[BK][LDB];  // [j][k] bf16 (linear, padded)

  const float* wi = w + (size_t)i * (J_ * K_);

  f32x4_t acc[4][4];
#pragma unroll
  for (int m = 0; m < 4; m++)
#pragma unroll
    for (int n = 0; n < 4; n++) acc[m][n] = (f32x4_t)(0.0f);

  // staging coords (per thread, fixed across K-steps)
  const int ar  = tid >> 1;         // 0..127  A row
  const int ajg = (tid & 1) * 16;   // 0/16    A j-group
  const int bjj = tid >> 3;         // 0..31   B j-row
  const int bkk = (tid & 7) * 16;   // 0..112  B k-offset

  for (int j0 = 0; j0 < J_; j0 += BK) {
    // --- stage A tile: c[b0+ar][j0+ajg .. +16)
    {
      const float* src = &cmat[(size_t)(b0 + ar) * J_ + j0 + ajg];
      float v[16];
#pragma unroll
      for (int q = 0; q < 4; q++) {
        f32x4_t t4 = *reinterpret_cast<const f32x4_t*>(src + q * 4);
        v[q * 4 + 0] = t4[0]; v[q * 4 + 1] = t4[1];
        v[q * 4 + 2] = t4[2]; v[q * 4 + 3] = t4[3];
      }
      uint* dst = reinterpret_cast<uint*>(&As[ar][ajg]);
#pragma unroll
      for (int q = 0; q < 8; q++) dst[q] = pack2bf(v[2 * q], v[2 * q + 1]);
    }
    // --- stage B tile: w[i][j0+bjj][k0+bkk .. +16)
    {
      const float* src = &wi[(size_t)(j0 + bjj) * K_ + k0 + bkk];
      float v[16];
#pragma unroll
      for (int q = 0; q < 4; q++) {
        f32x4_t t4 = *reinterpret_cast<const f32x4_t*>(src + q * 4);
        v[q * 4 + 0] = t4[0]; v[q * 4 + 1] = t4[1];
        v[q * 4 + 2] = t4[2]; v[q * 4 + 3] = t4[3];
      }
      uint* dst = reinterpret_cast<uint*>(&Bs[bjj][bkk]);
#pragma unroll
      for (int q = 0; q < 8; q++) dst[q] = pack2bf(v[2 * q], v[2 * q + 1]);
    }
    __syncthreads();

    short8_t af[4], bfrag[4];
#pragma unroll
    for (int m = 0; m < 4; m++) {
      const int row = wr * 64 + m * 16 + (lane & 15);
      af[m] = *reinterpret_cast<const short8_t*>(&As[row][(lane >> 4) * 8]);
    }
#pragma unroll
    for (int n = 0; n < 4; n++) {
      const int col = wc * 64 + n * 16 + (lane & 15);
      const int jb  = (lane >> 4) * 8;
      short8_t t;
#pragma unroll
      for (int e = 0; e < 8; e++) t[e] = (short)Bs[jb + e][col];
      bfrag[n] = t;
    }
#pragma unroll
    for (int m = 0; m < 4; m++)
#pragma unroll
      for (int n = 0; n < 4; n++)
        acc[m][n] = __builtin_amdgcn_mfma_f32_16x16x32_bf16(af[m], bfrag[n],
                                                            acc[m][n], 0, 0, 0);
    __syncthreads();
  }

  // --- write u tile as bf16: u[b][i][k]
#pragma unroll
  for (int m = 0; m < 4; m++) {
#pragma unroll
    for (int n = 0; n < 4; n++) {
      const int kcol = k0 + wc * 64 + n * 16 + (lane & 15);
#pragma unroll
      for (int r = 0; r < 4; r++) {
        const int brow = b0 + wr * 64 + m * 16 + (lane >> 4) * 4 + r;
        u[((size_t)brow * I_ + i) * K_ + kcol] = f2bf(acc[m][n][r]);
      }
    }
  }
}

// ---------------------------------------------------------------------------
// Pass 2: out[a][b][k] = sum_i s[a][b][i] * u[b][i][k] + bias[k]
// One block per b; thread = one k; s staged in LDS; fp32 accumulate.
// ---------------------------------------------------------------------------
__global__ __launch_bounds__(256) void pass2_kernel(
    const float* __restrict__ s, const ushort* __restrict__ u,
    const float* __restrict__ bias, float* __restrict__ out) {
  const int b   = blockIdx.x;
  const int tid = threadIdx.x;
  __shared__ float s_l[A_][I_];  // 8 KB
  for (int idx = tid; idx < A_ * I_; idx += 256) {
    const int a = idx >> 8;
    const int i = idx & 255;
    s_l[a][i] = s[(size_t)a * (B_ * I_) + (size_t)b * I_ + i];
  }
  __syncthreads();

  const int k = tid;
  float acc[A_];
#pragma unroll
  for (int a = 0; a < A_; a++) acc[a] = 0.0f;

  const ushort* ub = u + (size_t)b * (I_ * K_) + k;
  for (int i = 0; i < I_; i += 8) {
    float uv[8];
#pragma unroll
    for (int q = 0; q < 8; q++) uv[q] = bf2f(ub[(size_t)(i + q) * K_]);
#pragma unroll
    for (int a = 0; a < A_; a++) {
      const f32x4_t s0 = *reinterpret_cast<const f32x4_t*>(&s_l[a][i]);
      const f32x4_t s1 = *reinterpret_cast<const f32x4_t*>(&s_l[a][i + 4]);
      acc[a] += s0[0] * uv[0] + s0[1] * uv[1] + s0[2] * uv[2] + s0[3] * uv[3] +
                s1[0] * uv[4] + s1[1] * uv[5] + s1[2] * uv[6] + s1[3] * uv[7];
    }
  }

  const float bk = bias[k];
#pragma unroll
  for (int a = 0; a < A_; a++)
    out[((size_t)a * B_ + b) * K_ + k] = acc[a] + bk;
}

// ---------------------------------------------------------------------------
// Fallback (slow but correct, fp32): used only if workspace is too small.
// One block per b; thread = one k.
// ---------------------------------------------------------------------------
__global__ __launch_bounds__(256) void fallback_kernel(
    const float* __restrict__ s, const float* __restrict__ cmat,
    const float* __restrict__ w, const float* __restrict__ bias,
    float* __restrict__ out) {
  const int b = blockIdx.x;
  const int k = threadIdx.x;
  __shared__ float c_l[J_];
  __shared__ float s_l[A_][I_];
  for (int idx = threadIdx.x; idx < J_; idx += 256) c_l[idx] = cmat[(size_t)b * J_ + idx];
  for (int idx = threadIdx.x; idx < A_ * I_; idx += 256) {
    const int a = idx >> 8;
    const int i = idx & 255;
    s_l[a][i] = s[(size_t)a * (B_ * I_) + (size_t)b * I_ + i];
  }
  __syncthreads();
  float acc[A_];
#pragma unroll
  for (int a = 0; a < A_; a++) acc[a] = 0.0f;
  for (int i = 0; i < I_; i++) {
    const float* wrow = w + (size_t)i * (J_ * K_) + k;
    float inner = 0.0f;
    for (int j = 0; j < J_; j++) inner += c_l[j] * wrow[(size_t)j * K_];
#pragma unroll
    for (int a = 0; a < A_; a++) acc[a] += s_l[a][i] * inner;
  }
#pragma unroll
  for (int a = 0; a < A_; a++)
    out[((size_t)a * B_ + b) * K_ + k] = acc[a] + bias[k];
}

extern "C" void kernel_launch(void* const* d_in, const int* in_sizes, int n_in,
                              void* d_out, int out_size, void* d_ws, size_t ws_size,
                              hipStream_t stream) {
  const float* s    = (const float*)d_in[0];  // (A,B,I)
  const float* cmat = (const float*)d_in[1];  // (B,J)
  const float* w    = (const float*)d_in[2];  // (I,J,K)
  const float* bias = (const float*)d_in[3];  // (K,)
  float* out = (float*)d_out;

  const size_t need = (size_t)B_ * I_ * K_ * sizeof(ushort);  // 33.6 MB
  if (ws_size >= need) {
    ushort* u = (ushort*)d_ws;
    pass1_kernel<<<dim3(I_, B_ / BM, K_ / BN), dim3(256), 0, stream>>>(cmat, w, u);
    pass2_kernel<<<dim3(B_), dim3(256), 0, stream>>>(s, u, bias, out);
  } else {
    fallback_kernel<<<dim3(B_), dim3(256), 0, stream>>>(s, cmat, w, bias, out);
  }
}

// Round 2
// 46.100 us; speedup vs baseline: 1.0451x; 1.0451x over previous
//
#include <hip/hip_runtime.h>
#include <hip/hip_bf16.h>

#define A_ 8
#define B_ 256
#define I_ 256
#define J_ 256
#define K_ 256

typedef __attribute__((ext_vector_type(8))) short short8_t;
typedef __attribute__((ext_vector_type(4))) float f32x4_t;
typedef __attribute__((ext_vector_type(4))) uint u32x4_t;

static __device__ __forceinline__ uint pack2bf(float a, float b) {
  float2 f2; f2.x = a; f2.y = b;
  __hip_bfloat162 h2 = __float22bfloat162_rn(f2);
  uint r;
  __builtin_memcpy(&r, &h2, 4);
  return r;
}

static __device__ __forceinline__ ushort f2bf(float f) {
  __hip_bfloat16 h = __float2bfloat16(f);
  ushort us;
  __builtin_memcpy(&us, &h, 2);
  return us;
}

static __device__ __forceinline__ float bf2f(ushort h) {
  uint u = ((uint)h) << 16;
  float f;
  __builtin_memcpy(&f, &u, 4);
  return f;
}

// ---------------------------------------------------------------------------
// Prepass: cbf[b][j] = bf16(c[b][j])  (65536 elems, 64 blocks x 256 thr x 4)
// ---------------------------------------------------------------------------
__global__ __launch_bounds__(256) void prepass_kernel(
    const float* __restrict__ c, ushort* __restrict__ cbf) {
  const int idx = blockIdx.x * 256 + threadIdx.x;
  const f32x4_t v = *reinterpret_cast<const f32x4_t*>(c + (size_t)idx * 4);
  uint2 r;
  r.x = pack2bf(v[0], v[1]);
  r.y = pack2bf(v[2], v[3]);
  *reinterpret_cast<uint2*>(cbf + (size_t)idx * 4) = r;
}

// ---------------------------------------------------------------------------
// Pass 1: u[b][i][k] = sum_j c[b][j] * w[i][j][k]  (u stored bf16)
// One block per i. 512 threads = 8 waves (2 b-rows x 4 k-cols), 256x256 tile.
// BK=32, double-buffered LDS, register prefetch of next j-tile.
// ---------------------------------------------------------------------------
#define BK 32
#define LDH 40  // padded row length (halves) for both As and Bt

__global__ __launch_bounds__(512, 2) void pass1_kernel(
    const ushort* __restrict__ cbf, const float* __restrict__ w,
    ushort* __restrict__ u) {
  const int i    = blockIdx.x;
  const int tid  = threadIdx.x;
  const int lane = tid & 63;
  const int wave = tid >> 6;
  const int wr   = wave >> 2;  // 0..1 : 128 b-rows each
  const int wc   = wave & 3;   // 0..3 : 64 k-cols each
  const int lrow = lane & 15;
  const int lhi  = lane >> 4;  // 0..3

  __shared__ ushort As[2][256][LDH];  // [b][j]
  __shared__ ushort Bt[2][256][LDH];  // [k][j]

  const float* wi = w + (size_t)i * (J_ * K_);

  f32x4_t acc[8][4];
#pragma unroll
  for (int m = 0; m < 8; m++)
#pragma unroll
    for (int n = 0; n < 4; n++) acc[m][n] = (f32x4_t)(0.0f);

  // staging assignment (fixed per thread)
  const int ar = tid >> 1;          // 0..255 : A row (b)
  const int aj = (tid & 1) * 16;    // 0/16   : A j-offset (halves)
  const int bk = tid & 255;         // 0..255 : B k column
  const int bj = (tid >> 8) * 16;   // 0/16   : B j-base

  short8_t a8[2];
  float brg[16];

  auto LOAD = [&](int j0) {
    const ushort* sa = cbf + (size_t)ar * J_ + j0 + aj;
    a8[0] = *reinterpret_cast<const short8_t*>(sa);
    a8[1] = *reinterpret_cast<const short8_t*>(sa + 8);
    const float* sb = wi + (size_t)(j0 + bj) * K_ + bk;
#pragma unroll
    for (int q = 0; q < 16; q++) brg[q] = sb[(size_t)q * K_];
  };

  auto STORE = [&](int buf) {
    *reinterpret_cast<short8_t*>(&As[buf][ar][aj])     = a8[0];
    *reinterpret_cast<short8_t*>(&As[buf][ar][aj + 8]) = a8[1];
    u32x4_t t0, t1;
#pragma unroll
    for (int q = 0; q < 4; q++) t0[q] = pack2bf(brg[2 * q], brg[2 * q + 1]);
#pragma unroll
    for (int q = 0; q < 4; q++) t1[q] = pack2bf(brg[8 + 2 * q], brg[9 + 2 * q]);
    *reinterpret_cast<u32x4_t*>(&Bt[buf][bk][bj])     = t0;
    *reinterpret_cast<u32x4_t*>(&Bt[buf][bk][bj + 8]) = t1;
  };

  LOAD(0);
  STORE(0);
  __syncthreads();

  for (int t = 0; t < 8; ++t) {
    if (t < 7) LOAD((t + 1) * BK);  // prefetch next j-tile into regs
    const int buf = t & 1;
    short8_t afr[8], bfr[4];
#pragma unroll
    for (int m = 0; m < 8; m++)
      afr[m] = *reinterpret_cast<const short8_t*>(
          &As[buf][wr * 128 + m * 16 + lrow][lhi * 8]);
#pragma unroll
    for (int n = 0; n < 4; n++)
      bfr[n] = *reinterpret_cast<const short8_t*>(
          &Bt[buf][wc * 64 + n * 16 + lrow][lhi * 8]);
#pragma unroll
    for (int m = 0; m < 8; m++)
#pragma unroll
      for (int n = 0; n < 4; n++)
        acc[m][n] = __builtin_amdgcn_mfma_f32_16x16x32_bf16(afr[m], bfr[n],
                                                            acc[m][n], 0, 0, 0);
    if (t < 7) STORE(buf ^ 1);  // convert + write into the other buffer
    __syncthreads();
  }

  // epilogue: u[b][i][k] bf16
#pragma unroll
  for (int m = 0; m < 8; m++) {
    const int brow = wr * 128 + m * 16 + lhi * 4;
#pragma unroll
    for (int n = 0; n < 4; n++) {
      const int kc = wc * 64 + n * 16 + lrow;
      ushort* up = u + ((size_t)brow * I_ + i) * K_ + kc;
#pragma unroll
      for (int r = 0; r < 4; r++)
        up[(size_t)r * (I_ * K_)] = f2bf(acc[m][n][r]);
    }
  }
}

// ---------------------------------------------------------------------------
// Pass 2: out[a][b][k] = sum_i s[a][b][i] * u[b][i][k] + bias[k]
// Grid (B, 2): block handles 4 a's. Thread: 8 k (dwordx4 u loads) x 32 i,
// then LDS tree-reduce over the 8 i-groups.
// ---------------------------------------------------------------------------
__global__ __launch_bounds__(256) void pass2_kernel(
    const float* __restrict__ s, const ushort* __restrict__ u,
    const float* __restrict__ bias, float* __restrict__ out) {
  const int b   = blockIdx.x;
  const int a0  = blockIdx.y * 4;
  const int tid = threadIdx.x;
  __shared__ float s_l[4][I_];      // 4 KB
  __shared__ float red[8][4][K_];   // 32 KB

#pragma unroll
  for (int v = 0; v < 4; v++) {
    const int idx = tid + v * 256;
    const int a = idx >> 8, ii = idx & 255;
    s_l[a][ii] = s[((size_t)(a0 + a) * B_ + b) * I_ + ii];
  }
  __syncthreads();

  const int kb = (tid & 31) * 8;
  const int ig = tid >> 5;
  float acc[4][8];
#pragma unroll
  for (int a = 0; a < 4; a++)
#pragma unroll
    for (int q = 0; q < 8; q++) acc[a][q] = 0.0f;

  const ushort* ub = u + ((size_t)b * I_ + ig * 32) * K_ + kb;
  for (int ii = 0; ii < 32; ++ii) {
    const short8_t uv = *reinterpret_cast<const short8_t*>(ub + (size_t)ii * K_);
    float f[8];
#pragma unroll
    for (int q = 0; q < 8; q++) f[q] = bf2f((ushort)uv[q]);
    const int i = ig * 32 + ii;
#pragma unroll
    for (int a = 0; a < 4; a++) {
      const float sa = s_l[a][i];
#pragma unroll
      for (int q = 0; q < 8; q++) acc[a][q] += sa * f[q];
    }
  }

#pragma unroll
  for (int a = 0; a < 4; a++) {
    f32x4_t r0, r1;
#pragma unroll
    for (int q = 0; q < 4; q++) { r0[q] = acc[a][q]; r1[q] = acc[a][4 + q]; }
    *reinterpret_cast<f32x4_t*>(&red[ig][a][kb])     = r0;
    *reinterpret_cast<f32x4_t*>(&red[ig][a][kb + 4]) = r1;
  }
  __syncthreads();

#pragma unroll
  for (int v = 0; v < 4; v++) {
    const int k = tid;
    float sum = 0.0f;
#pragma unroll
    for (int g = 0; g < 8; g++) sum += red[g][v][k];
    out[((size_t)(a0 + v) * B_ + b) * K_ + k] = sum + bias[k];
  }
}

// ---------------------------------------------------------------------------
// Fallback (slow but correct, fp32): used only if workspace is too small.
// ---------------------------------------------------------------------------
__global__ __launch_bounds__(256) void fallback_kernel(
    const float* __restrict__ s, const float* __restrict__ cmat,
    const float* __restrict__ w, const float* __restrict__ bias,
    float* __restrict__ out) {
  const int b = blockIdx.x;
  const int k = threadIdx.x;
  __shared__ float c_l[J_];
  __shared__ float s_l[A_][I_];
  for (int idx = threadIdx.x; idx < J_; idx += 256) c_l[idx] = cmat[(size_t)b * J_ + idx];
  for (int idx = threadIdx.x; idx < A_ * I_; idx += 256) {
    const int a = idx >> 8;
    const int i = idx & 255;
    s_l[a][i] = s[(size_t)a * (B_ * I_) + (size_t)b * I_ + i];
  }
  __syncthreads();
  float acc[A_];
#pragma unroll
  for (int a = 0; a < A_; a++) acc[a] = 0.0f;
  for (int i = 0; i < I_; i++) {
    const float* wrow = w + (size_t)i * (J_ * K_) + k;
    float inner = 0.0f;
    for (int j = 0; j < J_; j++) inner += c_l[j] * wrow[(size_t)j * K_];
#pragma unroll
    for (int a = 0; a < A_; a++) acc[a] += s_l[a][i] * inner;
  }
#pragma unroll
  for (int a = 0; a < A_; a++)
    out[((size_t)a * B_ + b) * K_ + k] = acc[a] + bias[k];
}

extern "C" void kernel_launch(void* const* d_in, const int* in_sizes, int n_in,
                              void* d_out, int out_size, void* d_ws, size_t ws_size,
                              hipStream_t stream) {
  const float* s    = (const float*)d_in[0];  // (A,B,I)
  const float* cmat = (const float*)d_in[1];  // (B,J)
  const float* w    = (const float*)d_in[2];  // (I,J,K)
  const float* bias = (const float*)d_in[3];  // (K,)
  float* out = (float*)d_out;

  const size_t u_elems = (size_t)B_ * I_ * K_;
  const size_t need = u_elems * sizeof(ushort) + (size_t)B_ * J_ * sizeof(ushort);
  if (ws_size >= need) {
    ushort* u   = (ushort*)d_ws;
    ushort* cbf = (ushort*)d_ws + u_elems;
    prepass_kernel<<<dim3((B_ * J_) / (256 * 4)), dim3(256), 0, stream>>>(cmat, cbf);
    pass1_kernel<<<dim3(I_), dim3(512), 0, stream>>>(cbf, w, u);
    pass2_kernel<<<dim3(B_, 2), dim3(256), 0, stream>>>(s, u, bias, out);
  } else {
    fallback_kernel<<<dim3(B_), dim3(256), 0, stream>>>(s, cmat, w, bias, out);
  }
}

// Round 3
// 42.243 us; speedup vs baseline: 1.1406x; 1.0913x over previous
//
#include <hip/hip_runtime.h>
#include <hip/hip_bf16.h>

#define A_ 8
#define B_ 256
#define I_ 256
#define J_ 256
#define K_ 256

typedef __attribute__((ext_vector_type(8))) short short8_t;
typedef __attribute__((ext_vector_type(4))) float f32x4_t;
typedef __attribute__((ext_vector_type(4))) uint u32x4_t;

static __device__ __forceinline__ uint pack2bf(float a, float b) {
  float2 f2; f2.x = a; f2.y = b;
  __hip_bfloat162 h2 = __float22bfloat162_rn(f2);
  uint r;
  __builtin_memcpy(&r, &h2, 4);
  return r;
}

static __device__ __forceinline__ ushort f2bf(float f) {
  __hip_bfloat16 h = __float2bfloat16(f);
  ushort us;
  __builtin_memcpy(&us, &h, 2);
  return us;
}

static __device__ __forceinline__ float bf2f(ushort h) {
  uint u = ((uint)h) << 16;
  float f;
  __builtin_memcpy(&f, &u, 4);
  return f;
}

// ---------------------------------------------------------------------------
// Prepass: cbf[b][j] = bf16(c[b][j])
// ---------------------------------------------------------------------------
__global__ __launch_bounds__(256) void prepass_kernel(
    const float* __restrict__ c, ushort* __restrict__ cbf) {
  const int idx = blockIdx.x * 256 + threadIdx.x;
  const f32x4_t v = *reinterpret_cast<const f32x4_t*>(c + (size_t)idx * 4);
  uint2 r;
  r.x = pack2bf(v[0], v[1]);
  r.y = pack2bf(v[2], v[3]);
  *reinterpret_cast<uint2*>(cbf + (size_t)idx * 4) = r;
}

// ---------------------------------------------------------------------------
// Pass 1: u[b][i][k] = sum_j c[b][j] * w[i][j][k]  (u stored bf16)
// Grid (i, k-quarter) = (256,4). 256 threads = 4 waves, each 64(b) x 64(k).
// A-frags straight from global (cbf, L2-hot), ping-pong prefetched.
// B tile (w, fp32->bf16 transposed in regs) double-buffered in small LDS.
// ---------------------------------------------------------------------------
#define BK 32
#define LDB 40  // Bt row length in halves (80 B, 16B-aligned, ~2-way banks)

__global__ __launch_bounds__(256, 2) void pass1_kernel(
    const ushort* __restrict__ cbf, const float* __restrict__ w,
    ushort* __restrict__ u) {
  const int i    = blockIdx.x;
  const int k0   = blockIdx.y * 64;
  const int tid  = threadIdx.x;
  const int lane = tid & 63;
  const int wave = tid >> 6;   // b-quadrant (0..3)
  const int lrow = lane & 15;
  const int lhi  = lane >> 4;  // 0..3

  __shared__ ushort Bt[2][64][LDB];  // [k][j] bf16, double-buffered (10 KB)

  const float* wi = w + (size_t)i * (J_ * K_) + k0;

  // B staging coords: thread = one k column, 8 consecutive j rows
  const int bk = tid & 63;
  const int jb = (tid >> 6) * 8;

  // A frag row base (direct-from-global)
  const int arow = wave * 64 + lrow;

  f32x4_t acc[4][4];
#pragma unroll
  for (int m = 0; m < 4; m++)
#pragma unroll
    for (int n = 0; n < 4; n++) acc[m][n] = (f32x4_t)(0.0f);

  float    brg[2][8];
  short8_t afr[2][4];

#define LOADB(p, j0)                                                       \
  {                                                                        \
    const float* sb = wi + (size_t)((j0) + jb) * K_ + bk;                  \
    _Pragma("unroll") for (int q = 0; q < 8; q++)                          \
        brg[p][q] = sb[(size_t)q * K_];                                    \
  }
#define LOADA(p, j0)                                                       \
  {                                                                        \
    _Pragma("unroll") for (int m = 0; m < 4; m++)                          \
        afr[p][m] = *reinterpret_cast<const short8_t*>(                    \
            cbf + (size_t)(arow + m * 16) * J_ + (j0) + lhi * 8);          \
  }
#define STOREB(buf, p)                                                     \
  {                                                                        \
    u32x4_t t4;                                                            \
    _Pragma("unroll") for (int q = 0; q < 4; q++)                          \
        t4[q] = pack2bf(brg[p][2 * q], brg[p][2 * q + 1]);                 \
    *reinterpret_cast<u32x4_t*>(&Bt[buf][bk][jb]) = t4;                    \
  }

  LOADB(0, 0);
  LOADA(0, 0);
  STOREB(0, 0);
  __syncthreads();

#pragma unroll
  for (int t = 0; t < 8; ++t) {
    const int cur = t & 1;
    const int nxt = cur ^ 1;
    if (t < 7) {
      LOADB(nxt, (t + 1) * BK);
      LOADA(nxt, (t + 1) * BK);
    }
    short8_t bfr[4];
#pragma unroll
    for (int n = 0; n < 4; n++)
      bfr[n] = *reinterpret_cast<const short8_t*>(
          &Bt[cur][n * 16 + lrow][lhi * 8]);
#pragma unroll
    for (int m = 0; m < 4; m++)
#pragma unroll
      for (int n = 0; n < 4; n++)
        acc[m][n] = __builtin_amdgcn_mfma_f32_16x16x32_bf16(
            afr[cur][m], bfr[n], acc[m][n], 0, 0, 0);
    if (t < 7) STOREB(nxt, nxt);
    __syncthreads();
  }

  // epilogue: u[b][i][k] bf16
#pragma unroll
  for (int m = 0; m < 4; m++) {
    const int brow = wave * 64 + m * 16 + lhi * 4;
#pragma unroll
    for (int n = 0; n < 4; n++) {
      const int kc = k0 + n * 16 + lrow;
      ushort* up = u + ((size_t)brow * I_ + i) * K_ + kc;
#pragma unroll
      for (int r = 0; r < 4; r++)
        up[(size_t)r * (I_ * K_)] = f2bf(acc[m][n][r]);
    }
  }
#undef LOADB
#undef LOADA
#undef STOREB
}

// ---------------------------------------------------------------------------
// Pass 2: out[a][b][k] = sum_i s[a][b][i] * u[b][i][k] + bias[k]
// Grid (B, 2): block handles 4 a's. Thread: 8 k (short8 u loads) x 32 i,
// then LDS tree-reduce over the 8 i-groups.
// ---------------------------------------------------------------------------
__global__ __launch_bounds__(256) void pass2_kernel(
    const float* __restrict__ s, const ushort* __restrict__ u,
    const float* __restrict__ bias, float* __restrict__ out) {
  const int b   = blockIdx.x;
  const int a0  = blockIdx.y * 4;
  const int tid = threadIdx.x;
  __shared__ float s_l[4][I_];      // 4 KB
  __shared__ float red[8][4][K_];   // 32 KB

#pragma unroll
  for (int v = 0; v < 4; v++) {
    const int idx = tid + v * 256;
    const int a = idx >> 8, ii = idx & 255;
    s_l[a][ii] = s[((size_t)(a0 + a) * B_ + b) * I_ + ii];
  }
  __syncthreads();

  const int kb = (tid & 31) * 8;
  const int ig = tid >> 5;
  float acc[4][8];
#pragma unroll
  for (int a = 0; a < 4; a++)
#pragma unroll
    for (int q = 0; q < 8; q++) acc[a][q] = 0.0f;

  const ushort* ub = u + ((size_t)b * I_ + ig * 32) * K_ + kb;
  for (int ii = 0; ii < 32; ++ii) {
    const short8_t uv = *reinterpret_cast<const short8_t*>(ub + (size_t)ii * K_);
    float f[8];
#pragma unroll
    for (int q = 0; q < 8; q++) f[q] = bf2f((ushort)uv[q]);
    const int i = ig * 32 + ii;
#pragma unroll
    for (int a = 0; a < 4; a++) {
      const float sa = s_l[a][i];
#pragma unroll
      for (int q = 0; q < 8; q++) acc[a][q] += sa * f[q];
    }
  }

#pragma unroll
  for (int a = 0; a < 4; a++) {
    f32x4_t r0, r1;
#pragma unroll
    for (int q = 0; q < 4; q++) { r0[q] = acc[a][q]; r1[q] = acc[a][4 + q]; }
    *reinterpret_cast<f32x4_t*>(&red[ig][a][kb])     = r0;
    *reinterpret_cast<f32x4_t*>(&red[ig][a][kb + 4]) = r1;
  }
  __syncthreads();

#pragma unroll
  for (int v = 0; v < 4; v++) {
    const int k = tid;
    float sum = 0.0f;
#pragma unroll
    for (int g = 0; g < 8; g++) sum += red[g][v][k];
    out[((size_t)(a0 + v) * B_ + b) * K_ + k] = sum + bias[k];
  }
}

// ---------------------------------------------------------------------------
// Fallback (slow but correct, fp32): used only if workspace is too small.
// ---------------------------------------------------------------------------
__global__ __launch_bounds__(256) void fallback_kernel(
    const float* __restrict__ s, const float* __restrict__ cmat,
    const float* __restrict__ w, const float* __restrict__ bias,
    float* __restrict__ out) {
  const int b = blockIdx.x;
  const int k = threadIdx.x;
  __shared__ float c_l[J_];
  __shared__ float s_l[A_][I_];
  for (int idx = threadIdx.x; idx < J_; idx += 256) c_l[idx] = cmat[(size_t)b * J_ + idx];
  for (int idx = threadIdx.x; idx < A_ * I_; idx += 256) {
    const int a = idx >> 8;
    const int i = idx & 255;
    s_l[a][i] = s[(size_t)a * (B_ * I_) + (size_t)b * I_ + i];
  }
  __syncthreads();
  float acc[A_];
#pragma unroll
  for (int a = 0; a < A_; a++) acc[a] = 0.0f;
  for (int i = 0; i < I_; i++) {
    const float* wrow = w + (size_t)i * (J_ * K_) + k;
    float inner = 0.0f;
    for (int j = 0; j < J_; j++) inner += c_l[j] * wrow[(size_t)j * K_];
#pragma unroll
    for (int a = 0; a < A_; a++) acc[a] += s_l[a][i] * inner;
  }
#pragma unroll
  for (int a = 0; a < A_; a++)
    out[((size_t)a * B_ + b) * K_ + k] = acc[a] + bias[k];
}

extern "C" void kernel_launch(void* const* d_in, const int* in_sizes, int n_in,
                              void* d_out, int out_size, void* d_ws, size_t ws_size,
                              hipStream_t stream) {
  const float* s    = (const float*)d_in[0];  // (A,B,I)
  const float* cmat = (const float*)d_in[1];  // (B,J)
  const float* w    = (const float*)d_in[2];  // (I,J,K)
  const float* bias = (const float*)d_in[3];  // (K,)
  float* out = (float*)d_out;

  const size_t u_elems = (size_t)B_ * I_ * K_;
  const size_t need = u_elems * sizeof(ushort) + (size_t)B_ * J_ * sizeof(ushort);
  if (ws_size >= need) {
    ushort* u   = (ushort*)d_ws;
    ushort* cbf = (ushort*)d_ws + u_elems;
    prepass_kernel<<<dim3((B_ * J_) / (256 * 4)), dim3(256), 0, stream>>>(cmat, cbf);
    pass1_kernel<<<dim3(I_, 4), dim3(256), 0, stream>>>(cbf, w, u);
    pass2_kernel<<<dim3(B_, 2), dim3(256), 0, stream>>>(s, u, bias, out);
  } else {
    fallback_kernel<<<dim3(B_), dim3(256), 0, stream>>>(s, cmat, w, bias, out);
  }
}